// Round 1
// baseline (913.273 us; speedup 1.0000x reference)
//
#include <hip/hip_runtime.h>

// ---------------------------------------------------------------------------
// dist = (1/(N*P*M)) * sum_{n,m,p} || src[p] - pe[n,m] + 1e-6 ||_2
// P=50 (pad 64), M=197, N=1024 (N*M = 201728 = 1576*128), D=768
//
// Expansion: ||a'-b||^2 = ||a'||^2 + ||b||^2 - 2 a'.b  with a' = src + eps.
// Cross term via bf16 MFMA 16x16x32; norms in fp32.
// ws layout: [0..6304) partials f32[1576]; [8192..8448) na f32[64];
//            [16384..114688) A bf16[64][768]
// ---------------------------------------------------------------------------

typedef __attribute__((ext_vector_type(8))) short bf16x8;
typedef __attribute__((ext_vector_type(4))) float f32x4;

#define D_DIM 768
#define NM_TOTAL 201728
#define COLS_PER_WG 128
#define NUM_WG (NM_TOTAL / COLS_PER_WG)   // 1576

__device__ __forceinline__ unsigned short f2bf(float f) {
  // round-to-nearest-even fp32 -> bf16 (inputs are finite normals)
  unsigned int u = __float_as_uint(f);
  u += 0x7FFFu + ((u >> 16) & 1u);
  return (unsigned short)(u >> 16);
}

__global__ void prep_kernel(const float* __restrict__ src,
                            short* __restrict__ aW,
                            float* __restrict__ na) {
  const int r = blockIdx.x;        // 0..63, one wave per row
  const int lane = threadIdx.x;    // 0..63
  float sq = 0.f;
#pragma unroll
  for (int j = 0; j < 12; ++j) {
    const int c = lane + j * 64;
    float v = 0.f;
    if (r < 50) v = src[r * D_DIM + c] + 1e-6f;
    sq += v * v;
    aW[r * D_DIM + c] = (short)f2bf(v);
  }
#pragma unroll
  for (int m = 32; m >= 1; m >>= 1) sq += __shfl_xor(sq, m);
  if (lane == 0) na[r] = sq;
}

__global__ __launch_bounds__(512, 4) void dist_kernel(
    const float* __restrict__ pe,
    const short* __restrict__ aW,
    const float* __restrict__ na,
    float* __restrict__ partials) {
  const int tid  = threadIdx.x;
  const int wave = tid >> 6;
  const int lane = tid & 63;
  const int quad = lane >> 4;
  const int l16  = lane & 15;

  // this lane's patch column (also the column it loads B data for)
  const int col = blockIdx.x * COLS_PER_WG + wave * 16 + l16;
  const float* brow = pe + (size_t)col * D_DIM + quad * 8;

  const short* a0p = aW + (size_t)(0 * 16 + l16) * D_DIM + quad * 8;
  const short* a1p = aW + (size_t)(1 * 16 + l16) * D_DIM + quad * 8;
  const short* a2p = aW + (size_t)(2 * 16 + l16) * D_DIM + quad * 8;
  const short* a3p = aW + (size_t)(3 * 16 + l16) * D_DIM + quad * 8;

  f32x4 acc0 = {0.f, 0.f, 0.f, 0.f};
  f32x4 acc1 = {0.f, 0.f, 0.f, 0.f};
  f32x4 acc2 = {0.f, 0.f, 0.f, 0.f};
  f32x4 acc3 = {0.f, 0.f, 0.f, 0.f};
  float nb = 0.f;

#pragma unroll 2
  for (int it = 0; it < 24; ++it) {
    const float4 f0 = *(const float4*)(brow + it * 32);
    const float4 f1 = *(const float4*)(brow + it * 32 + 4);

    bf16x8 af0 = *(const bf16x8*)(a0p + it * 32);
    bf16x8 af1 = *(const bf16x8*)(a1p + it * 32);
    bf16x8 af2 = *(const bf16x8*)(a2p + it * 32);
    bf16x8 af3 = *(const bf16x8*)(a3p + it * 32);

    nb = fmaf(f0.x, f0.x, nb); nb = fmaf(f0.y, f0.y, nb);
    nb = fmaf(f0.z, f0.z, nb); nb = fmaf(f0.w, f0.w, nb);
    nb = fmaf(f1.x, f1.x, nb); nb = fmaf(f1.y, f1.y, nb);
    nb = fmaf(f1.z, f1.z, nb); nb = fmaf(f1.w, f1.w, nb);

    union { bf16x8 v; unsigned short u[8]; } b;
    b.u[0] = f2bf(f0.x); b.u[1] = f2bf(f0.y);
    b.u[2] = f2bf(f0.z); b.u[3] = f2bf(f0.w);
    b.u[4] = f2bf(f1.x); b.u[5] = f2bf(f1.y);
    b.u[6] = f2bf(f1.z); b.u[7] = f2bf(f1.w);

    acc0 = __builtin_amdgcn_mfma_f32_16x16x32_bf16(af0, b.v, acc0, 0, 0, 0);
    acc1 = __builtin_amdgcn_mfma_f32_16x16x32_bf16(af1, b.v, acc1, 0, 0, 0);
    acc2 = __builtin_amdgcn_mfma_f32_16x16x32_bf16(af2, b.v, acc2, 0, 0, 0);
    acc3 = __builtin_amdgcn_mfma_f32_16x16x32_bf16(af3, b.v, acc3, 0, 0, 0);
  }

  // nb currently holds this lane's quad-partial of ||b_col||^2; sum the 4 quads
  nb += __shfl_xor(nb, 16);
  nb += __shfl_xor(nb, 32);

  // epilogue: C[p][col] lives at col=lane&15, row p_local = quad*4 + reg
  float s = 0.f;
  {
    const float* accf;
    f32x4 accs[4] = {acc0, acc1, acc2, acc3};
#pragma unroll
    for (int t = 0; t < 4; ++t) {
#pragma unroll
      for (int r = 0; r < 4; ++r) {
        const int p = t * 16 + quad * 4 + r;
        if (p < 50) {
          const float c = accs[t][r];
          const float d2 = fmaxf(na[p] + nb - 2.f * c, 0.f);
          s += sqrtf(d2);
        }
      }
    }
    (void)accf;
  }

  // wave reduction
#pragma unroll
  for (int m = 32; m >= 1; m >>= 1) s += __shfl_xor(s, m);

  __shared__ float wsum[8];
  if (lane == 0) wsum[wave] = s;
  __syncthreads();
  if (tid == 0) {
    float t = 0.f;
#pragma unroll
    for (int i = 0; i < 8; ++i) t += wsum[i];
    partials[blockIdx.x] = t;
  }
}

__global__ void finalize_kernel(const float* __restrict__ partials,
                                float* __restrict__ out) {
  __shared__ float red[256];
  float s = 0.f;
  for (int i = threadIdx.x; i < NUM_WG; i += 256) s += partials[i];
  red[threadIdx.x] = s;
  __syncthreads();
  for (int step = 128; step >= 1; step >>= 1) {
    if (threadIdx.x < step) red[threadIdx.x] += red[threadIdx.x + step];
    __syncthreads();
  }
  // mean over P*M = 9850 per step, then / N = 1024  ->  1/10086400
  if (threadIdx.x == 0) out[0] = red[0] * (1.0f / 10086400.0f);
}

extern "C" void kernel_launch(void* const* d_in, const int* in_sizes, int n_in,
                              void* d_out, int out_size, void* d_ws, size_t ws_size,
                              hipStream_t stream) {
  const float* src = (const float*)d_in[0];   // [50, 768]
  const float* pe  = (const float*)d_in[1];   // [1024, 197, 768]
  // d_in[2] (src_task) unused by the math
  float* out = (float*)d_out;

  char* ws = (char*)d_ws;
  float* partials = (float*)ws;                 // 1576 f32
  float* na       = (float*)(ws + 8192);        // 64 f32
  short* aW       = (short*)(ws + 16384);       // 64*768 bf16

  prep_kernel<<<64, 64, 0, stream>>>(src, aW, na);
  dist_kernel<<<NUM_WG, 512, 0, stream>>>(pe, aW, na, partials);
  finalize_kernel<<<1, 256, 0, stream>>>(partials, out);
}

// Round 2
// 843.648 us; speedup vs baseline: 1.0825x; 1.0825x over previous
//
#include <hip/hip_runtime.h>

// ---------------------------------------------------------------------------
// dist = (1/(N*P*M)) * sum_{n,m,p} || src[p] - pe[n,m] + 1e-6 ||_2
// P=50 (pad 64), M=197, N=1024 (N*M = 201728 = 1576*128), D=768
//
// ||a'-b||^2 = ||a'||^2 + ||b||^2 - 2 a'.b, a' = src + eps. Cross term via
// bf16 MFMA 16x16x32. B (pe) staged to LDS via global_load_lds(16B) in
// 256-B contiguous per-col segments, XOR-swizzled for bank-uniform ds_read.
// ws: [0) partials f32[1576]; [8192) na f32[64]; [16384) A bf16[64][768]
// ---------------------------------------------------------------------------

typedef __attribute__((ext_vector_type(8))) short bf16x8;
typedef __attribute__((ext_vector_type(4))) float f32x4;

#define D_DIM 768
#define NM_TOTAL 201728
#define COLS_PER_WG 128
#define NUM_WG (NM_TOTAL / COLS_PER_WG)   // 1576
#define KC 64                              // fp32 k-elements per col per chunk
#define NCHUNK (D_DIM / KC)                // 12

__device__ __forceinline__ unsigned short f2bf(float f) {
  unsigned int u = __float_as_uint(f);
  u += 0x7FFFu + ((u >> 16) & 1u);
  return (unsigned short)(u >> 16);
}

__global__ void prep_kernel(const float* __restrict__ src,
                            short* __restrict__ aW,
                            float* __restrict__ na) {
  const int r = blockIdx.x;        // 0..63, one wave per row
  const int lane = threadIdx.x;    // 0..63
  float sq = 0.f;
#pragma unroll
  for (int j = 0; j < 12; ++j) {
    const int c = lane + j * 64;
    float v = 0.f;
    if (r < 50) v = src[r * D_DIM + c] + 1e-6f;
    sq += v * v;
    aW[r * D_DIM + c] = (short)f2bf(v);
  }
#pragma unroll
  for (int m = 32; m >= 1; m >>= 1) sq += __shfl_xor(sq, m);
  if (lane == 0) na[r] = sq;
}

__global__ __launch_bounds__(512, 4) void dist_kernel(
    const float* __restrict__ pe,
    const short* __restrict__ aW,
    const float* __restrict__ na,
    float* __restrict__ partials) {
  // 2 x 128 cols x 64 k fp32 = 2 x 32 KB (exactly 64 KB static LDS)
  __shared__ __attribute__((aligned(16))) float buf[2][COLS_PER_WG * KC];

  const int tid  = threadIdx.x;
  const int wave = tid >> 6;
  const int lane = tid & 63;
  const int quad = lane >> 4;
  const int l16  = lane & 15;
  const int colL = wave * 16 + l16;          // this lane's patch col (local)
  const int col0 = blockIdx.x * COLS_PER_WG;

  // staging mapping: per round r the wave fills cols [wave*16+r*4, +4),
  // lane L -> col wave*16+r*4+(L>>4), 16-B chunk position L&15.
  const int s_sub = lane >> 4;               // 0..3
  const int cpos  = lane & 15;               // chunk position within col seg

  const short* a0p = aW + (size_t)(0 * 16 + l16) * D_DIM;
  const short* a1p = aW + (size_t)(1 * 16 + l16) * D_DIM;
  const short* a2p = aW + (size_t)(2 * 16 + l16) * D_DIM;
  const short* a3p = aW + (size_t)(3 * 16 + l16) * D_DIM;

  f32x4 acc0 = {0.f, 0.f, 0.f, 0.f};
  f32x4 acc1 = {0.f, 0.f, 0.f, 0.f};
  f32x4 acc2 = {0.f, 0.f, 0.f, 0.f};
  f32x4 acc3 = {0.f, 0.f, 0.f, 0.f};
  float nb = 0.f;

  // ---- prologue: stage chunk 0 into buf[0] ----
#pragma unroll
  for (int r = 0; r < 4; ++r) {
    const int cl   = wave * 16 + r * 4 + s_sub;
    const int cdat = cpos ^ (cl & 15);       // XOR swizzle (bank-uniform reads)
    const float* g = pe + (size_t)(col0 + cl) * D_DIM + cdat * 4;
    __builtin_amdgcn_global_load_lds(
        (const __attribute__((address_space(1))) void*)g,
        (__attribute__((address_space(3))) void*)&buf[0][(wave * 16 + r * 4) * KC],
        16, 0, 0);
  }
  __syncthreads();

  for (int it = 0; it < NCHUNK; ++it) {
    const int cur = it & 1;
    if (it + 1 < NCHUNK) {
#pragma unroll
      for (int r = 0; r < 4; ++r) {
        const int cl   = wave * 16 + r * 4 + s_sub;
        const int cdat = cpos ^ (cl & 15);
        const float* g = pe + (size_t)(col0 + cl) * D_DIM + (it + 1) * KC + cdat * 4;
        __builtin_amdgcn_global_load_lds(
            (const __attribute__((address_space(1))) void*)g,
            (__attribute__((address_space(3))) void*)&buf[cur ^ 1][(wave * 16 + r * 4) * KC],
            16, 0, 0);
      }
    }

    const float* bufc = buf[cur];
#pragma unroll
    for (int s = 0; s < 2; ++s) {
      const int kbase = it * KC + s * 32;
      const int P0 = s * 8 + quad * 2;       // data chunk indices P0, P0+1
      const f32x4 u0 = *(const f32x4*)&bufc[colL * KC + ((P0 ^ l16) << 2)];
      const f32x4 u1 = *(const f32x4*)&bufc[colL * KC + (((P0 + 1) ^ l16) << 2)];

      nb = fmaf(u0.x, u0.x, nb); nb = fmaf(u0.y, u0.y, nb);
      nb = fmaf(u0.z, u0.z, nb); nb = fmaf(u0.w, u0.w, nb);
      nb = fmaf(u1.x, u1.x, nb); nb = fmaf(u1.y, u1.y, nb);
      nb = fmaf(u1.z, u1.z, nb); nb = fmaf(u1.w, u1.w, nb);

      union { bf16x8 v; unsigned short u[8]; } b;
      b.u[0] = f2bf(u0.x); b.u[1] = f2bf(u0.y);
      b.u[2] = f2bf(u0.z); b.u[3] = f2bf(u0.w);
      b.u[4] = f2bf(u1.x); b.u[5] = f2bf(u1.y);
      b.u[6] = f2bf(u1.z); b.u[7] = f2bf(u1.w);

      bf16x8 af0 = *(const bf16x8*)(a0p + kbase + quad * 8);
      bf16x8 af1 = *(const bf16x8*)(a1p + kbase + quad * 8);
      bf16x8 af2 = *(const bf16x8*)(a2p + kbase + quad * 8);
      bf16x8 af3 = *(const bf16x8*)(a3p + kbase + quad * 8);

      acc0 = __builtin_amdgcn_mfma_f32_16x16x32_bf16(af0, b.v, acc0, 0, 0, 0);
      acc1 = __builtin_amdgcn_mfma_f32_16x16x32_bf16(af1, b.v, acc1, 0, 0, 0);
      acc2 = __builtin_amdgcn_mfma_f32_16x16x32_bf16(af2, b.v, acc2, 0, 0, 0);
      acc3 = __builtin_amdgcn_mfma_f32_16x16x32_bf16(af3, b.v, acc3, 0, 0, 0);
    }
    __syncthreads();   // drains stage(next) vmcnt + protects buffer reuse
  }

  // nb holds this lane's quad-partial of ||b_col||^2; sum the 4 quads
  nb += __shfl_xor(nb, 16);
  nb += __shfl_xor(nb, 32);

  // epilogue: C[p][col] at col=lane&15, row p_local = quad*4 + reg
  float s = 0.f;
  {
    f32x4 accs[4] = {acc0, acc1, acc2, acc3};
#pragma unroll
    for (int t = 0; t < 4; ++t) {
#pragma unroll
      for (int r = 0; r < 4; ++r) {
        const int p = t * 16 + quad * 4 + r;
        if (p < 50) {
          const float c = accs[t][r];
          const float d2 = fmaxf(na[p] + nb - 2.f * c, 0.f);
          s += sqrtf(d2);
        }
      }
    }
  }

#pragma unroll
  for (int m = 32; m >= 1; m >>= 1) s += __shfl_xor(s, m);

  float* wsum = (float*)buf;   // LDS free after final barrier
  if (lane == 0) wsum[wave] = s;
  __syncthreads();
  if (tid == 0) {
    float t = 0.f;
#pragma unroll
    for (int i = 0; i < 8; ++i) t += wsum[i];
    partials[blockIdx.x] = t;
  }
}

__global__ void finalize_kernel(const float* __restrict__ partials,
                                float* __restrict__ out) {
  __shared__ float red[256];
  float s = 0.f;
  for (int i = threadIdx.x; i < NUM_WG; i += 256) s += partials[i];
  red[threadIdx.x] = s;
  __syncthreads();
  for (int step = 128; step >= 1; step >>= 1) {
    if (threadIdx.x < step) red[threadIdx.x] += red[threadIdx.x + step];
    __syncthreads();
  }
  // mean over P*M = 9850, then / N = 1024  ->  1/10086400
  if (threadIdx.x == 0) out[0] = red[0] * (1.0f / 10086400.0f);
}

extern "C" void kernel_launch(void* const* d_in, const int* in_sizes, int n_in,
                              void* d_out, int out_size, void* d_ws, size_t ws_size,
                              hipStream_t stream) {
  const float* src = (const float*)d_in[0];   // [50, 768]
  const float* pe  = (const float*)d_in[1];   // [1024, 197, 768]
  float* out = (float*)d_out;

  char* ws = (char*)d_ws;
  float* partials = (float*)ws;                 // 1576 f32
  float* na       = (float*)(ws + 8192);        // 64 f32
  short* aW       = (short*)(ws + 16384);       // 64*768 bf16

  prep_kernel<<<64, 64, 0, stream>>>(src, aW, na);
  dist_kernel<<<NUM_WG, 512, 0, stream>>>(pe, aW, na, partials);
  finalize_kernel<<<1, 256, 0, stream>>>(partials, out);
}

// Round 3
// 841.314 us; speedup vs baseline: 1.0855x; 1.0028x over previous
//
#include <hip/hip_runtime.h>

// ---------------------------------------------------------------------------
// dist = (1/(N*P*M)) * sum_{n,m,p} || src[p] - pe[n,m] + 1e-6 ||_2
// P=50 (pad 64), M=197, N=1024 (N*M = 201728 = 1576*128), D=768
//
// ||a'-b||^2 = ||a'||^2 + ||b||^2 - 2 a'.b, a' = src + eps. Cross term via
// bf16 MFMA 16x16x32.
//
// R3: barrier-free wave-private K-loop. Each wave owns 16 cols and its own
// 2x4KB LDS double-buffer; global_load_lds producer == ds_read consumer, so
// the only sync needed is an in-wave `s_waitcnt vmcnt(4)` (inline asm).
// Queue order per chunk: [A-frags x8][stage(next) x4] -> vmcnt(4) retires
// prev stage + A, keeps next stage in flight. No __syncthreads in the loop.
// ws: [0) partials f32[1576]; [8192) na f32[64]; [16384) A bf16[64][768]
// ---------------------------------------------------------------------------

typedef __attribute__((ext_vector_type(8))) short bf16x8;
typedef __attribute__((ext_vector_type(4))) float f32x4;

#define D_DIM 768
#define NM_TOTAL 201728
#define COLS_PER_WG 128
#define NUM_WG (NM_TOTAL / COLS_PER_WG)   // 1576
#define KC 64                              // fp32 k-elements per col per chunk
#define NCHUNK (D_DIM / KC)                // 12
#define CPW 16                             // cols per wave

__device__ __forceinline__ unsigned short f2bf(float f) {
  unsigned int u = __float_as_uint(f);
  u += 0x7FFFu + ((u >> 16) & 1u);
  return (unsigned short)(u >> 16);
}

__global__ void prep_kernel(const float* __restrict__ src,
                            short* __restrict__ aW,
                            float* __restrict__ na) {
  const int r = blockIdx.x;        // 0..63, one wave per row
  const int lane = threadIdx.x;    // 0..63
  float sq = 0.f;
#pragma unroll
  for (int j = 0; j < 12; ++j) {
    const int c = lane + j * 64;
    float v = 0.f;
    if (r < 50) v = src[r * D_DIM + c] + 1e-6f;
    sq += v * v;
    aW[r * D_DIM + c] = (short)f2bf(v);
  }
#pragma unroll
  for (int m = 32; m >= 1; m >>= 1) sq += __shfl_xor(sq, m);
  if (lane == 0) na[r] = sq;
}

__global__ __launch_bounds__(512, 4) void dist_kernel(
    const float* __restrict__ pe,
    const short* __restrict__ aW,
    const float* __restrict__ na,
    float* __restrict__ partials) {
  // 8 waves x 2 buffers x (16 cols x 64 k fp32 = 4 KB) = 64 KB static LDS
  __shared__ __attribute__((aligned(16))) float buf[8][2][CPW * KC];

  const int tid  = threadIdx.x;
  const int wave = tid >> 6;
  const int lane = tid & 63;
  const int quad = lane >> 4;
  const int l16  = lane & 15;

  const int colbase = blockIdx.x * COLS_PER_WG + wave * CPW;

  // staging: round r fills local cols [r*4, r*4+4): lane L -> col r*4+(L>>4),
  // 16-B chunk position L&15, XOR-swizzled source so reads are bank-uniform.
  const int s_sub = lane >> 4;
  const int cpos  = lane & 15;

  f32x4 acc0 = {0.f, 0.f, 0.f, 0.f};
  f32x4 acc1 = {0.f, 0.f, 0.f, 0.f};
  f32x4 acc2 = {0.f, 0.f, 0.f, 0.f};
  f32x4 acc3 = {0.f, 0.f, 0.f, 0.f};
  float nb = 0.f;

  // ---- prologue: stage chunk 0 into buf[wave][0] ----
#pragma unroll
  for (int r = 0; r < 4; ++r) {
    const int cl = r * 4 + s_sub;
    const float* g = pe + (size_t)(colbase + cl) * D_DIM + ((cpos ^ cl) << 2);
    __builtin_amdgcn_global_load_lds(
        (const __attribute__((address_space(1))) void*)g,
        (__attribute__((address_space(3))) void*)&buf[wave][0][(r * 4) * KC],
        16, 0, 0);
  }

  for (int it = 0; it < NCHUNK; ++it) {
    const int cur = it & 1;

    // A-fragments for this chunk: 8 x 16B register preloads (L2-hot).
    // Issued BEFORE the stage loads so vmcnt(4) retires them too.
    bf16x8 af[2][4];
#pragma unroll
    for (int s = 0; s < 2; ++s)
#pragma unroll
      for (int t = 0; t < 4; ++t)
        af[s][t] = *(const bf16x8*)(aW + (size_t)(t * 16 + l16) * D_DIM +
                                    it * KC + s * 32 + quad * 8);

    if (it + 1 < NCHUNK) {
#pragma unroll
      for (int r = 0; r < 4; ++r) {
        const int cl = r * 4 + s_sub;
        const float* g = pe + (size_t)(colbase + cl) * D_DIM + (it + 1) * KC +
                         ((cpos ^ cl) << 2);
        __builtin_amdgcn_global_load_lds(
            (const __attribute__((address_space(1))) void*)g,
            (__attribute__((address_space(3))) void*)&buf[wave][cur ^ 1][(r * 4) * KC],
            16, 0, 0);
      }
      // retire prev stage (oldest 4) + A loads; keep next stage in flight
      asm volatile("s_waitcnt vmcnt(4)" ::: "memory");
    } else {
      asm volatile("s_waitcnt vmcnt(0)" ::: "memory");
    }

    const float* bufc = buf[wave][cur];
#pragma unroll
    for (int s = 0; s < 2; ++s) {
      const int P0 = s * 8 + quad * 2;   // data 16B-chunk indices P0, P0+1
      const f32x4 u0 = *(const f32x4*)&bufc[l16 * KC + ((P0 ^ l16) << 2)];
      const f32x4 u1 = *(const f32x4*)&bufc[l16 * KC + (((P0 + 1) ^ l16) << 2)];

      nb = fmaf(u0.x, u0.x, nb); nb = fmaf(u0.y, u0.y, nb);
      nb = fmaf(u0.z, u0.z, nb); nb = fmaf(u0.w, u0.w, nb);
      nb = fmaf(u1.x, u1.x, nb); nb = fmaf(u1.y, u1.y, nb);
      nb = fmaf(u1.z, u1.z, nb); nb = fmaf(u1.w, u1.w, nb);

      union { bf16x8 v; unsigned short u[8]; } b;
      b.u[0] = f2bf(u0.x); b.u[1] = f2bf(u0.y);
      b.u[2] = f2bf(u0.z); b.u[3] = f2bf(u0.w);
      b.u[4] = f2bf(u1.x); b.u[5] = f2bf(u1.y);
      b.u[6] = f2bf(u1.z); b.u[7] = f2bf(u1.w);

      acc0 = __builtin_amdgcn_mfma_f32_16x16x32_bf16(af[s][0], b.v, acc0, 0, 0, 0);
      acc1 = __builtin_amdgcn_mfma_f32_16x16x32_bf16(af[s][1], b.v, acc1, 0, 0, 0);
      acc2 = __builtin_amdgcn_mfma_f32_16x16x32_bf16(af[s][2], b.v, acc2, 0, 0, 0);
      acc3 = __builtin_amdgcn_mfma_f32_16x16x32_bf16(af[s][3], b.v, acc3, 0, 0, 0);
    }
  }

  // nb holds this lane's quad-partial of ||b_col||^2; sum the 4 quads
  nb += __shfl_xor(nb, 16);
  nb += __shfl_xor(nb, 32);

  // epilogue: C[p][col] at col=lane&15, row p_local = quad*4 + reg
  float s = 0.f;
  {
    f32x4 accs[4] = {acc0, acc1, acc2, acc3};
#pragma unroll
    for (int t = 0; t < 4; ++t) {
#pragma unroll
      for (int r = 0; r < 4; ++r) {
        const int p = t * 16 + quad * 4 + r;
        if (p < 50) {
          const float c = accs[t][r];
          const float d2 = fmaxf(na[p] + nb - 2.f * c, 0.f);
          s += sqrtf(d2);
        }
      }
    }
  }

#pragma unroll
  for (int m = 32; m >= 1; m >>= 1) s += __shfl_xor(s, m);

  // cross-wave reduction: waves are desynced, so barrier before reusing buf
  __syncthreads();
  float* wsum = (float*)buf;
  if (lane == 0) wsum[wave] = s;
  __syncthreads();
  if (tid == 0) {
    float t = 0.f;
#pragma unroll
    for (int i = 0; i < 8; ++i) t += wsum[i];
    partials[blockIdx.x] = t;
  }
}

__global__ void finalize_kernel(const float* __restrict__ partials,
                                float* __restrict__ out) {
  __shared__ float red[256];
  float s = 0.f;
  for (int i = threadIdx.x; i < NUM_WG; i += 256) s += partials[i];
  red[threadIdx.x] = s;
  __syncthreads();
  for (int step = 128; step >= 1; step >>= 1) {
    if (threadIdx.x < step) red[threadIdx.x] += red[threadIdx.x + step];
    __syncthreads();
  }
  // mean over P*M = 9850, then / N = 1024  ->  1/10086400
  if (threadIdx.x == 0) out[0] = red[0] * (1.0f / 10086400.0f);
}

extern "C" void kernel_launch(void* const* d_in, const int* in_sizes, int n_in,
                              void* d_out, int out_size, void* d_ws, size_t ws_size,
                              hipStream_t stream) {
  const float* src = (const float*)d_in[0];   // [50, 768]
  const float* pe  = (const float*)d_in[1];   // [1024, 197, 768]
  float* out = (float*)d_out;

  char* ws = (char*)d_ws;
  float* partials = (float*)ws;                 // 1576 f32
  float* na       = (float*)(ws + 8192);        // 64 f32
  short* aW       = (short*)(ws + 16384);       // 64*768 bf16

  prep_kernel<<<64, 64, 0, stream>>>(src, aW, na);
  dist_kernel<<<NUM_WG, 512, 0, stream>>>(pe, aW, na, partials);
  finalize_kernel<<<1, 256, 0, stream>>>(partials, out);
}